// Round 1
// baseline (2484.548 us; speedup 1.0000x reference)
//
#include <hip/hip_runtime.h>

#define NFEAT 128
#define H 20
#define DH 64

// ---------------- GCN encoder ----------------

__global__ __launch_bounds__(256) void k_init(float* __restrict__ acc, int* __restrict__ deg, int N) {
    int t = blockIdx.x * blockDim.x + threadIdx.x;
    if (t < N * H) acc[t] = 0.f;
    if (t < N) deg[t] = 0;
}

__global__ __launch_bounds__(256) void k_deg(const int* __restrict__ cols, int* __restrict__ deg, int E) {
    int t = blockIdx.x * blockDim.x + threadIdx.x;
    if (t < E) atomicAdd(&deg[cols[t]], 1);
}

// xw = x @ W_gc   (one thread per node, W in LDS, broadcast reads)
__global__ __launch_bounds__(256) void k_xw(const float* __restrict__ x, const float* __restrict__ Wgc,
                                            float* __restrict__ xw, int N) {
    __shared__ float Ws[NFEAT * H];  // 10 KB
    for (int i = threadIdx.x; i < NFEAT * H; i += blockDim.x) Ws[i] = Wgc[i];
    __syncthreads();
    int n = blockIdx.x * blockDim.x + threadIdx.x;
    if (n >= N) return;
    float acc[H];
#pragma unroll
    for (int j = 0; j < H; j++) acc[j] = 0.f;
    const float4* x4 = (const float4*)(x + (size_t)n * NFEAT);
#pragma unroll 4
    for (int k4 = 0; k4 < NFEAT / 4; k4++) {
        float4 xv = x4[k4];
#pragma unroll
        for (int s = 0; s < 4; s++) {
            float xk = (s == 0) ? xv.x : (s == 1) ? xv.y : (s == 2) ? xv.z : xv.w;
            const float4* wrow = (const float4*)(Ws + (k4 * 4 + s) * H);  // row*80B, 16B aligned
#pragma unroll
            for (int q = 0; q < 5; q++) {
                float4 w = wrow[q];
                acc[q * 4 + 0] += xk * w.x;
                acc[q * 4 + 1] += xk * w.y;
                acc[q * 4 + 2] += xk * w.z;
                acc[q * 4 + 3] += xk * w.w;
            }
        }
    }
    float4* o = (float4*)(xw + (size_t)n * H);
#pragma unroll
    for (int q = 0; q < 5; q++) o[q] = make_float4(acc[q * 4 + 0], acc[q * 4 + 1], acc[q * 4 + 2], acc[q * 4 + 3]);
}

// dinv[n] = rsqrt(deg+1) (self-loop);  xs = xw * dinv[n]
__global__ __launch_bounds__(256) void k_dinv_xs(const float* __restrict__ xw, const int* __restrict__ deg,
                                                 float* __restrict__ xs, float* __restrict__ dinv, int N) {
    int t = blockIdx.x * blockDim.x + threadIdx.x;
    if (t >= N * H) return;
    int n = t / H;
    float di = rsqrtf((float)(deg[n] + 1));
    xs[t] = xw[t] * di;
    if (t - n * H == 0) dinv[n] = di;
}

// acc[c] += xs[r] for every edge (20 fp32 atomics / edge)
__global__ __launch_bounds__(256) void k_scatter(const int* __restrict__ rows, const int* __restrict__ cols,
                                                 const float* __restrict__ xs, float* __restrict__ acc, int E) {
    int e = blockIdx.x * blockDim.x + threadIdx.x;
    if (e >= E) return;
    int r = rows[e], c = cols[e];
    const float4* xr4 = (const float4*)(xs + (size_t)r * H);
    float* a = acc + (size_t)c * H;
#pragma unroll
    for (int q = 0; q < 5; q++) {
        float4 v = xr4[q];
        atomicAdd(a + q * 4 + 0, v.x);
        atomicAdd(a + q * 4 + 1, v.y);
        atomicAdd(a + q * 4 + 2, v.z);
        atomicAdd(a + q * 4 + 3, v.w);
    }
}

// x1 = relu(dinv[n]*(acc + xs) + b_gc)
__global__ __launch_bounds__(256) void k_x1(const float* __restrict__ acc, const float* __restrict__ xs,
                                            const float* __restrict__ dinv, const float* __restrict__ bgc,
                                            float* __restrict__ x1, int N) {
    int t = blockIdx.x * blockDim.x + threadIdx.x;
    if (t >= N * H) return;
    int n = t / H;
    int j = t - n * H;
    float v = dinv[n] * (acc[t] + xs[t]) + bgc[j];
    x1[t] = fmaxf(v, 0.f);
}

// ---------------- per-edge variational head + decoder ----------------
// one thread per edge; all weight loads are wave-uniform float4 (expect s_load scalarization)
__global__ __launch_bounds__(256) void k_mlp(
    const float* __restrict__ x1, const int* __restrict__ rows, const int* __restrict__ cols,
    const int* __restrict__ node_id, const float* __restrict__ noise_n, const float* __restrict__ noise_u,
    const float* __restrict__ W_mu, const float* __restrict__ b_mu,
    const float* __restrict__ W_var, const float* __restrict__ b_var,
    const float* __restrict__ W_d1, const float* __restrict__ b_d1,
    const float* __restrict__ W_d2, const float* __restrict__ b_d2,
    float* __restrict__ out, int E) {
    __shared__ float ne[H];
    if (threadIdx.x < H) ne[threadIdx.x] = x1[(size_t)node_id[0] * H + threadIdx.x];
    __syncthreads();
    int e = blockIdx.x * blockDim.x + threadIdx.x;
    if (e >= E) return;
    int r = rows[e], c = cols[e];

    float xr[H], xc[H];
    {
        const float4* p = (const float4*)(x1 + (size_t)r * H);
#pragma unroll
        for (int q = 0; q < 5; q++) {
            float4 v = p[q];
            xr[q * 4 + 0] = v.x; xr[q * 4 + 1] = v.y; xr[q * 4 + 2] = v.z; xr[q * 4 + 3] = v.w;
        }
        const float4* pc = (const float4*)(x1 + (size_t)c * H);
#pragma unroll
        for (int q = 0; q < 5; q++) {
            float4 v = pc[q];
            xc[q * 4 + 0] = v.x; xc[q * 4 + 1] = v.y; xc[q * 4 + 2] = v.z; xc[q * 4 + 3] = v.w;
        }
    }

    float mu[H], lv[H];
#pragma unroll
    for (int j = 0; j < H; j++) { mu[j] = b_mu[j]; lv[j] = b_var[j]; }

    const float4* Wmu4 = (const float4*)W_mu;    // [60][20] row-major, rows of 5 float4
    const float4* Wvar4 = (const float4*)W_var;
#pragma unroll
    for (int k = 0; k < H; k++) {
        float a = xr[k], b = xc[k], d = ne[k];
#pragma unroll
        for (int q = 0; q < 5; q++) {
            float4 wa = Wmu4[k * 5 + q];
            float4 wb = Wmu4[(k + H) * 5 + q];
            float4 wd = Wmu4[(k + 2 * H) * 5 + q];
            mu[q * 4 + 0] += a * wa.x + b * wb.x + d * wd.x;
            mu[q * 4 + 1] += a * wa.y + b * wb.y + d * wd.y;
            mu[q * 4 + 2] += a * wa.z + b * wb.z + d * wd.z;
            mu[q * 4 + 3] += a * wa.w + b * wb.w + d * wd.w;
            float4 va = Wvar4[k * 5 + q];
            float4 vb = Wvar4[(k + H) * 5 + q];
            float4 vd = Wvar4[(k + 2 * H) * 5 + q];
            lv[q * 4 + 0] += a * va.x + b * vb.x + d * vd.x;
            lv[q * 4 + 1] += a * va.y + b * vb.y + d * vd.y;
            lv[q * 4 + 2] += a * va.z + b * vb.z + d * vd.z;
            lv[q * 4 + 3] += a * va.w + b * vb.w + d * vd.w;
        }
    }

    // z = mu + exp(lv) * noise
    float z[H];
    {
        const float4* nn4 = (const float4*)(noise_n + (size_t)e * H);
#pragma unroll
        for (int q = 0; q < 5; q++) {
            float4 nv = nn4[q];
            z[q * 4 + 0] = mu[q * 4 + 0] + expf(lv[q * 4 + 0]) * nv.x;
            z[q * 4 + 1] = mu[q * 4 + 1] + expf(lv[q * 4 + 1]) * nv.y;
            z[q * 4 + 2] = mu[q * 4 + 2] + expf(lv[q * 4 + 2]) * nv.z;
            z[q * 4 + 3] = mu[q * 4 + 3] + expf(lv[q * 4 + 3]) * nv.w;
        }
    }

    // h = relu(z @ W_d1 + b_d1)
    float h[DH];
    {
        const float4* b4 = (const float4*)b_d1;
#pragma unroll
        for (int q = 0; q < DH / 4; q++) {
            float4 bb = b4[q];
            h[q * 4 + 0] = bb.x; h[q * 4 + 1] = bb.y; h[q * 4 + 2] = bb.z; h[q * 4 + 3] = bb.w;
        }
        const float4* W4 = (const float4*)W_d1;  // [20][64]
#pragma unroll
        for (int k = 0; k < H; k++) {
            float zk = z[k];
#pragma unroll
            for (int q = 0; q < DH / 4; q++) {
                float4 w = W4[k * (DH / 4) + q];
                h[q * 4 + 0] += zk * w.x;
                h[q * 4 + 1] += zk * w.y;
                h[q * 4 + 2] += zk * w.z;
                h[q * 4 + 3] += zk * w.w;
            }
        }
    }

    // sw = relu(relu(h) @ W_d2 + b_d2)
    float sw = b_d2[0];
    {
        const float4* W4 = (const float4*)W_d2;
#pragma unroll
        for (int q = 0; q < DH / 4; q++) {
            float4 w = W4[q];
            sw += fmaxf(h[q * 4 + 0], 0.f) * w.x;
            sw += fmaxf(h[q * 4 + 1], 0.f) * w.y;
            sw += fmaxf(h[q * 4 + 2], 0.f) * w.z;
            sw += fmaxf(h[q * 4 + 3], 0.f) * w.w;
        }
    }
    sw = fmaxf(sw, 0.f);

    // gumbel-sigmoid gate
    float u = noise_u[e];
    float ev = 0.9999f - 0.9998f * u;          // (bias-(1-bias))*u + (1-bias), bias=1e-4
    float gate = logf(ev) - logf(1.f - ev) + sw;
    out[e] = 1.f / (1.f + expf(-gate));
}

extern "C" void kernel_launch(void* const* d_in, const int* in_sizes, int n_in,
                              void* d_out, int out_size, void* d_ws, size_t ws_size,
                              hipStream_t stream) {
    const int N = in_sizes[0] / NFEAT;   // 50000
    const int E = in_sizes[1] / 2;       // 1600000

    const float* x       = (const float*)d_in[0];
    const int*   ei      = (const int*)d_in[1];
    const int*   rows    = ei;
    const int*   cols    = ei + E;
    const int*   node_id = (const int*)d_in[2];
    const float* noise_n = (const float*)d_in[3];
    const float* noise_u = (const float*)d_in[4];
    const float* Wgc  = (const float*)d_in[5];
    const float* bgc  = (const float*)d_in[6];
    const float* Wmu  = (const float*)d_in[7];
    const float* bmu  = (const float*)d_in[8];
    const float* Wvar = (const float*)d_in[9];
    const float* bvar = (const float*)d_in[10];
    const float* Wd1  = (const float*)d_in[11];
    const float* bd1  = (const float*)d_in[12];
    const float* Wd2  = (const float*)d_in[13];
    const float* bd2  = (const float*)d_in[14];
    float* out = (float*)d_out;

    // workspace layout (16B-aligned offsets); x1 reuses the xw buffer (xw dead after k_dinv_xs)
    char* ws = (char*)d_ws;
    int*   deg  = (int*)ws;                       // 200,000 B
    float* dinv = (float*)(ws + 200000);          // 200,000 B
    float* xw   = (float*)(ws + 400000);          // 4,000,000 B (reused as x1)
    float* xs   = (float*)(ws + 4400000);         // 4,000,000 B
    float* acc  = (float*)(ws + 8400000);         // 4,000,000 B
    float* x1   = xw;

    const int B = 256;
    int gNH = (N * H + B - 1) / B;
    int gN  = (N + B - 1) / B;
    int gE  = (E + B - 1) / B;

    k_init<<<gNH, B, 0, stream>>>(acc, deg, N);
    k_deg<<<gE, B, 0, stream>>>(cols, deg, E);
    k_xw<<<gN, B, 0, stream>>>(x, Wgc, xw, N);
    k_dinv_xs<<<gNH, B, 0, stream>>>(xw, deg, xs, dinv, N);
    k_scatter<<<gE, B, 0, stream>>>(rows, cols, xs, acc, E);
    k_x1<<<gNH, B, 0, stream>>>(acc, xs, dinv, bgc, x1, N);
    k_mlp<<<gE, B, 0, stream>>>(x1, rows, cols, node_id, noise_n, noise_u,
                                Wmu, bmu, Wvar, bvar, Wd1, bd1, Wd2, bd2, out, E);
}

// Round 2
// 1105.588 us; speedup vs baseline: 2.2473x; 2.2473x over previous
//
#include <hip/hip_runtime.h>

#define NFEAT 128
#define H 20
#define DH 64
#define SCAN_T 1024

// ---------------- GCN encoder (CSR gather formulation) ----------------

__global__ __launch_bounds__(256) void k_zero(int* __restrict__ deg, int N) {
    int t = blockIdx.x * blockDim.x + threadIdx.x;
    if (t < N) deg[t] = 0;
}

__global__ __launch_bounds__(256) void k_deg(const int* __restrict__ cols, int* __restrict__ deg, int E) {
    int t = blockIdx.x * blockDim.x + threadIdx.x;
    if (t < E) atomicAdd(&deg[cols[t]], 1);
}

// single-workgroup exclusive scan over deg -> offsets[0..N], cursor copy
__global__ __launch_bounds__(SCAN_T) void k_scan(const int* __restrict__ deg, int* __restrict__ offsets,
                                                 int* __restrict__ cursor, int N) {
    __shared__ int sums[SCAN_T];
    int t = threadIdx.x;
    int chunk = (N + SCAN_T - 1) / SCAN_T;
    int beg = t * chunk;
    int end = min(beg + chunk, N);
    int s = 0;
    for (int i = beg; i < end; i++) s += deg[i];
    sums[t] = s;
    __syncthreads();
    // Hillis-Steele inclusive scan
    for (int off = 1; off < SCAN_T; off <<= 1) {
        int v = (t >= off) ? sums[t - off] : 0;
        __syncthreads();
        sums[t] += v;
        __syncthreads();
    }
    int run = (t == 0) ? 0 : sums[t - 1];
    for (int i = beg; i < end; i++) {
        offsets[i] = run;
        cursor[i] = run;
        run += deg[i];
    }
    if (t == SCAN_T - 1) offsets[N] = sums[SCAN_T - 1];
}

// bucket edge sources by destination: srcs[offsets[c]..] = rows of in-edges of c
__global__ __launch_bounds__(256) void k_bucket(const int* __restrict__ rows, const int* __restrict__ cols,
                                                int* __restrict__ cursor, int* __restrict__ srcs, int E) {
    int e = blockIdx.x * blockDim.x + threadIdx.x;
    if (e >= E) return;
    int pos = atomicAdd(&cursor[cols[e]], 1);
    srcs[pos] = rows[e];
}

// xs = (x @ W_gc) * dinv[n];  dinv[n] = rsqrt(deg[n]+1)
__global__ __launch_bounds__(256) void k_xw_xs(const float* __restrict__ x, const float* __restrict__ Wgc,
                                               const int* __restrict__ deg,
                                               float* __restrict__ xs, float* __restrict__ dinv, int N) {
    __shared__ float Ws[NFEAT * H];  // 10 KB
    for (int i = threadIdx.x; i < NFEAT * H; i += blockDim.x) Ws[i] = Wgc[i];
    __syncthreads();
    int n = blockIdx.x * blockDim.x + threadIdx.x;
    if (n >= N) return;
    float acc[H];
#pragma unroll
    for (int j = 0; j < H; j++) acc[j] = 0.f;
    const float4* x4 = (const float4*)(x + (size_t)n * NFEAT);
#pragma unroll 4
    for (int k4 = 0; k4 < NFEAT / 4; k4++) {
        float4 xv = x4[k4];
#pragma unroll
        for (int s = 0; s < 4; s++) {
            float xk = (s == 0) ? xv.x : (s == 1) ? xv.y : (s == 2) ? xv.z : xv.w;
            const float4* wrow = (const float4*)(Ws + (k4 * 4 + s) * H);
#pragma unroll
            for (int q = 0; q < 5; q++) {
                float4 w = wrow[q];
                acc[q * 4 + 0] += xk * w.x;
                acc[q * 4 + 1] += xk * w.y;
                acc[q * 4 + 2] += xk * w.z;
                acc[q * 4 + 3] += xk * w.w;
            }
        }
    }
    float di = rsqrtf((float)(deg[n] + 1));
    dinv[n] = di;
    float4* o = (float4*)(xs + (size_t)n * H);
#pragma unroll
    for (int q = 0; q < 5; q++)
        o[q] = make_float4(acc[q * 4 + 0] * di, acc[q * 4 + 1] * di, acc[q * 4 + 2] * di, acc[q * 4 + 3] * di);
}

// x1[n] = relu(dinv[n] * (sum_{r in N(n)} xs[r] + xs[n]) + b_gc)
// one thread per (node, float4 chunk) — no atomics, gathers hit L2 (xs = 4MB)
__global__ __launch_bounds__(256) void k_gather(const float* __restrict__ xs, const int* __restrict__ srcs,
                                                const int* __restrict__ offsets, const float* __restrict__ dinv,
                                                const float* __restrict__ bgc, float* __restrict__ x1, int N) {
    int t = blockIdx.x * blockDim.x + threadIdx.x;
    if (t >= N * 5) return;
    int n = t / 5;
    int q = t - n * 5;
    int beg = offsets[n];
    int end = offsets[n + 1];
    float4 s = ((const float4*)(xs + (size_t)n * H))[q];  // self-loop term
#pragma unroll 4
    for (int i = beg; i < end; i++) {
        int r = srcs[i];
        float4 v = ((const float4*)(xs + (size_t)r * H))[q];
        s.x += v.x; s.y += v.y; s.z += v.z; s.w += v.w;
    }
    float di = dinv[n];
    float4 b = ((const float4*)bgc)[q];
    float4 o;
    o.x = fmaxf(di * s.x + b.x, 0.f);
    o.y = fmaxf(di * s.y + b.y, 0.f);
    o.z = fmaxf(di * s.z + b.z, 0.f);
    o.w = fmaxf(di * s.w + b.w, 0.f);
    ((float4*)(x1 + (size_t)n * H))[q] = o;
}

// ---------------- per-edge variational head + decoder ----------------
__global__ __launch_bounds__(256) void k_mlp(
    const float* __restrict__ x1, const int* __restrict__ rows, const int* __restrict__ cols,
    const int* __restrict__ node_id, const float* __restrict__ noise_n, const float* __restrict__ noise_u,
    const float* __restrict__ W_mu, const float* __restrict__ b_mu,
    const float* __restrict__ W_var, const float* __restrict__ b_var,
    const float* __restrict__ W_d1, const float* __restrict__ b_d1,
    const float* __restrict__ W_d2, const float* __restrict__ b_d2,
    float* __restrict__ out, int E) {
    __shared__ float ne[H];
    if (threadIdx.x < H) ne[threadIdx.x] = x1[(size_t)node_id[0] * H + threadIdx.x];
    __syncthreads();
    int e = blockIdx.x * blockDim.x + threadIdx.x;
    if (e >= E) return;
    int r = rows[e], c = cols[e];

    float xr[H], xc[H];
    {
        const float4* p = (const float4*)(x1 + (size_t)r * H);
#pragma unroll
        for (int q = 0; q < 5; q++) {
            float4 v = p[q];
            xr[q * 4 + 0] = v.x; xr[q * 4 + 1] = v.y; xr[q * 4 + 2] = v.z; xr[q * 4 + 3] = v.w;
        }
        const float4* pc = (const float4*)(x1 + (size_t)c * H);
#pragma unroll
        for (int q = 0; q < 5; q++) {
            float4 v = pc[q];
            xc[q * 4 + 0] = v.x; xc[q * 4 + 1] = v.y; xc[q * 4 + 2] = v.z; xc[q * 4 + 3] = v.w;
        }
    }

    float mu[H], lv[H];
#pragma unroll
    for (int j = 0; j < H; j++) { mu[j] = b_mu[j]; lv[j] = b_var[j]; }

    const float4* Wmu4 = (const float4*)W_mu;    // [60][20] row-major
    const float4* Wvar4 = (const float4*)W_var;
#pragma unroll
    for (int k = 0; k < H; k++) {
        float a = xr[k], b = xc[k], d = ne[k];
#pragma unroll
        for (int q = 0; q < 5; q++) {
            float4 wa = Wmu4[k * 5 + q];
            float4 wb = Wmu4[(k + H) * 5 + q];
            float4 wd = Wmu4[(k + 2 * H) * 5 + q];
            mu[q * 4 + 0] += a * wa.x + b * wb.x + d * wd.x;
            mu[q * 4 + 1] += a * wa.y + b * wb.y + d * wd.y;
            mu[q * 4 + 2] += a * wa.z + b * wb.z + d * wd.z;
            mu[q * 4 + 3] += a * wa.w + b * wb.w + d * wd.w;
            float4 va = Wvar4[k * 5 + q];
            float4 vb = Wvar4[(k + H) * 5 + q];
            float4 vd = Wvar4[(k + 2 * H) * 5 + q];
            lv[q * 4 + 0] += a * va.x + b * vb.x + d * vd.x;
            lv[q * 4 + 1] += a * va.y + b * vb.y + d * vd.y;
            lv[q * 4 + 2] += a * va.z + b * vb.z + d * vd.z;
            lv[q * 4 + 3] += a * va.w + b * vb.w + d * vd.w;
        }
    }

    float z[H];
    {
        const float4* nn4 = (const float4*)(noise_n + (size_t)e * H);
#pragma unroll
        for (int q = 0; q < 5; q++) {
            float4 nv = nn4[q];
            z[q * 4 + 0] = mu[q * 4 + 0] + expf(lv[q * 4 + 0]) * nv.x;
            z[q * 4 + 1] = mu[q * 4 + 1] + expf(lv[q * 4 + 1]) * nv.y;
            z[q * 4 + 2] = mu[q * 4 + 2] + expf(lv[q * 4 + 2]) * nv.z;
            z[q * 4 + 3] = mu[q * 4 + 3] + expf(lv[q * 4 + 3]) * nv.w;
        }
    }

    float h[DH];
    {
        const float4* b4 = (const float4*)b_d1;
#pragma unroll
        for (int q = 0; q < DH / 4; q++) {
            float4 bb = b4[q];
            h[q * 4 + 0] = bb.x; h[q * 4 + 1] = bb.y; h[q * 4 + 2] = bb.z; h[q * 4 + 3] = bb.w;
        }
        const float4* W4 = (const float4*)W_d1;  // [20][64]
#pragma unroll
        for (int k = 0; k < H; k++) {
            float zk = z[k];
#pragma unroll
            for (int q = 0; q < DH / 4; q++) {
                float4 w = W4[k * (DH / 4) + q];
                h[q * 4 + 0] += zk * w.x;
                h[q * 4 + 1] += zk * w.y;
                h[q * 4 + 2] += zk * w.z;
                h[q * 4 + 3] += zk * w.w;
            }
        }
    }

    float sw = b_d2[0];
    {
        const float4* W4 = (const float4*)W_d2;
#pragma unroll
        for (int q = 0; q < DH / 4; q++) {
            float4 w = W4[q];
            sw += fmaxf(h[q * 4 + 0], 0.f) * w.x;
            sw += fmaxf(h[q * 4 + 1], 0.f) * w.y;
            sw += fmaxf(h[q * 4 + 2], 0.f) * w.z;
            sw += fmaxf(h[q * 4 + 3], 0.f) * w.w;
        }
    }
    sw = fmaxf(sw, 0.f);

    float u = noise_u[e];
    float ev = 0.9999f - 0.9998f * u;
    float gate = logf(ev) - logf(1.f - ev) + sw;
    out[e] = 1.f / (1.f + expf(-gate));
}

extern "C" void kernel_launch(void* const* d_in, const int* in_sizes, int n_in,
                              void* d_out, int out_size, void* d_ws, size_t ws_size,
                              hipStream_t stream) {
    const int N = in_sizes[0] / NFEAT;   // 50000
    const int E = in_sizes[1] / 2;       // 1600000

    const float* x       = (const float*)d_in[0];
    const int*   ei      = (const int*)d_in[1];
    const int*   rows    = ei;
    const int*   cols    = ei + E;
    const int*   node_id = (const int*)d_in[2];
    const float* noise_n = (const float*)d_in[3];
    const float* noise_u = (const float*)d_in[4];
    const float* Wgc  = (const float*)d_in[5];
    const float* bgc  = (const float*)d_in[6];
    const float* Wmu  = (const float*)d_in[7];
    const float* bmu  = (const float*)d_in[8];
    const float* Wvar = (const float*)d_in[9];
    const float* bvar = (const float*)d_in[10];
    const float* Wd1  = (const float*)d_in[11];
    const float* bd1  = (const float*)d_in[12];
    const float* Wd2  = (const float*)d_in[13];
    const float* bd2  = (const float*)d_in[14];
    float* out = (float*)d_out;

    // workspace layout (16B-aligned offsets)
    char* ws = (char*)d_ws;
    int*   deg     = (int*)ws;                    //   200,000 B
    float* dinv    = (float*)(ws + 200000);       //   200,000 B
    int*   offsets = (int*)(ws + 400000);         //   200,016 B (N+1 ints)
    int*   cursor  = (int*)(ws + 600016);         //   200,000 B
    int*   srcs    = (int*)(ws + 800016);         // 6,400,000 B
    float* xs      = (float*)(ws + 7200016);      // 4,000,000 B
    float* x1      = (float*)(ws + 11200016);     // 4,000,000 B

    const int B = 256;
    int gN  = (N + B - 1) / B;
    int gN5 = (N * 5 + B - 1) / B;
    int gE  = (E + B - 1) / B;

    k_zero<<<gN, B, 0, stream>>>(deg, N);
    k_deg<<<gE, B, 0, stream>>>(cols, deg, E);
    k_scan<<<1, SCAN_T, 0, stream>>>(deg, offsets, cursor, N);
    k_bucket<<<gE, B, 0, stream>>>(rows, cols, cursor, srcs, E);
    k_xw_xs<<<gN, B, 0, stream>>>(x, Wgc, deg, xs, dinv, N);
    k_gather<<<gN5, B, 0, stream>>>(xs, srcs, offsets, dinv, bgc, x1, N);
    k_mlp<<<gE, B, 0, stream>>>(x1, rows, cols, node_id, noise_n, noise_u,
                                Wmu, bmu, Wvar, bvar, Wd1, bd1, Wd2, bd2, out, E);
}